// Round 12
// baseline (3119.654 us; speedup 1.0000x reference)
//
#include <hip/hip_runtime.h>

#define SEQ 2048
#define D 128

// ---------------------------------------------------------------------------
// Kernel 1: per-step J-independent quantities (fully parallel), UNNORMALIZED:
//   alpha_i  = k_s . q_i      (i <= s)
//   kqq[s]   = sum alpha_i^2          = l * (k^T Sqq_l k)
//   sl[s]    = sum alpha_i (v_s.v_i)  = l * (k^T Sqv_l v)
//   vv[s]    = v_s . v_s
//   U[s][c]  = sum_i q_i[c] alpha_i   = l * (Sqq_l k)[c]
//   invl[s]  = 1.0 / l   (fp64, for cost rescale)
// Adjacency scalars (for the scan's lagged-matvec corrections):
//   kq_adj[s] = k_{s-1} . q_s ; vv_adj[s] = v_s . v_{s-1} ; kU_adj[s] = k_{s-1} . U_s
// ---------------------------------------------------------------------------
__global__ __launch_bounds__(256) void precompute_kernel(
    const float* __restrict__ q, const float* __restrict__ k, const float* __restrict__ v,
    float* __restrict__ U, float* __restrict__ sl, float* __restrict__ kqq,
    float* __restrict__ vv, float* __restrict__ kq_adj, float* __restrict__ vv_adj,
    float* __restrict__ kU_adj, double* __restrict__ invl)
{
    const int s = blockIdx.x;
    const int tid = threadIdx.x;

    __shared__ float ks[D];
    __shared__ float vs[D];
    __shared__ float alpha[SEQ];
    __shared__ float red[8];
    __shared__ float upart[256];

    if (tid < D) ks[tid] = k[s * D + tid];
    else if (tid < 2 * D) vs[tid - D] = v[s * D + (tid - D)];
    __syncthreads();

    float p_a2 = 0.f, p_ab = 0.f;
    for (int i = tid; i <= s; i += 256) {
        const float4* qr = (const float4*)(q + (size_t)i * D);
        const float4* vr = (const float4*)(v + (size_t)i * D);
        float a = 0.f, b = 0.f;
#pragma unroll
        for (int j = 0; j < D / 4; ++j) {
            float4 q4 = qr[j];
            float4 v4 = vr[j];
            a += q4.x * ks[4 * j + 0] + q4.y * ks[4 * j + 1] + q4.z * ks[4 * j + 2] + q4.w * ks[4 * j + 3];
            b += v4.x * vs[4 * j + 0] + v4.y * vs[4 * j + 1] + v4.z * vs[4 * j + 2] + v4.w * vs[4 * j + 3];
        }
        alpha[i] = a;
        p_a2 += a * a;
        p_ab += a * b;
        if (i == s) vv[s] = b;  // v_s . v_s
    }
#pragma unroll
    for (int off = 1; off < 64; off <<= 1) {
        p_a2 += __shfl_xor(p_a2, off);
        p_ab += __shfl_xor(p_ab, off);
    }
    const int wid = tid >> 6;
    if ((tid & 63) == 0) { red[wid] = p_a2; red[4 + wid] = p_ab; }
    __syncthreads();  // also makes alpha[] visible to everyone
    if (tid == 0) {
        kqq[s] = red[0] + red[1] + red[2] + red[3];
        sl[s]  = red[4] + red[5] + red[6] + red[7];
        invl[s] = 1.0 / (double)(s + 1);
    }

    // ---- adjacency dots: wave 0 -> kq_adj[s+1], wave 1 -> vv_adj[s] ----
    if (tid < 64) {
        if (s + 1 < SEQ) {
            float p2 = ks[tid] * q[(size_t)(s + 1) * D + tid]
                     + ks[tid + 64] * q[(size_t)(s + 1) * D + 64 + tid];
#pragma unroll
            for (int off = 1; off < 64; off <<= 1) p2 += __shfl_xor(p2, off);
            if (tid == 0) kq_adj[s + 1] = p2;
        }
        if (s == 0 && tid == 0) { kq_adj[0] = 0.f; kU_adj[0] = 0.f; vv_adj[0] = 0.f; }
    } else if (tid < 128 && s > 0) {
        const int t2 = tid - 64;
        float p2 = vs[t2] * v[(size_t)(s - 1) * D + t2]
                 + vs[t2 + 64] * v[(size_t)(s - 1) * D + 64 + t2];
#pragma unroll
        for (int off = 1; off < 64; off <<= 1) p2 += __shfl_xor(p2, off);
        if (t2 == 0) vv_adj[s] = p2;
    }

    // pass 2: U[s][c] = sum_i q[i][c] * alpha[i], i parity-split over h,
    // 4 independent accumulators to break the dependent fma chain
    const int c = tid & (D - 1);
    const int h = tid >> 7;  // 0 or 1
    float a0 = 0.f, a1 = 0.f, a2 = 0.f, a3 = 0.f;
    int i = h;
    for (; i + 6 <= s; i += 8) {
        a0 = fmaf(q[(size_t)(i    ) * D + c], alpha[i    ], a0);
        a1 = fmaf(q[(size_t)(i + 2) * D + c], alpha[i + 2], a1);
        a2 = fmaf(q[(size_t)(i + 4) * D + c], alpha[i + 4], a2);
        a3 = fmaf(q[(size_t)(i + 6) * D + c], alpha[i + 6], a3);
    }
    for (; i <= s; i += 2) a0 = fmaf(q[(size_t)i * D + c], alpha[i], a0);
    upart[tid] = (a0 + a1) + (a2 + a3);
    __syncthreads();

    // U store + kU_adj[s] = k_{s-1}.U_s
    float kup = 0.f;
    if (tid < D) {
        const float uv = upart[tid] + upart[tid + D];
        U[(size_t)s * D + tid] = uv;
        if (s > 0) kup = uv * k[(size_t)(s - 1) * D + tid];
    }
#pragma unroll
    for (int off = 1; off < 64; off <<= 1) kup += __shfl_xor(kup, off);
    if (tid == 0)  red[0] = kup;
    if (tid == 64) red[1] = kup;
    __syncthreads();
    if (s > 0 && tid == 0) kU_adj[s] = red[0] + red[1];
}

// ---------------------------------------------------------------------------
// DPP helpers (R7/R10/R11-verified):
// ---------------------------------------------------------------------------
#define DPP_ADD(x, ctrl) \
    ((x) + __int_as_float(__builtin_amdgcn_update_dpp(0, __float_as_int(x), (ctrl), 0xf, 0xf, true)))
#define COMBINE8(x) do { x = DPP_ADD(x, 0xB1); x = DPP_ADD(x, 0x4E); x = DPP_ADD(x, 0x141); } while (0)
#define TAIL3(x)    do { x = DPP_ADD(x, 0x140); x = DPP_ADD(x, 0x142); x = DPP_ADD(x, 0x143); } while (0)
#define REDUCE16(x) do { x = DPP_ADD(x, 0xB1); x = DPP_ADD(x, 0x4E); x = DPP_ADD(x, 0x141); \
                         x = DPP_ADD(x, 0x140); } while (0)

#define UPDATE_J(MODE, WF, WI)                                                            \
    if ((MODE) == 2) {                                                                    \
        jr0.x = vcur*kk0.x; jr0.y = vcur*kk0.y; jr0.z = vcur*kk0.z; jr0.w = vcur*kk0.w;   \
        jr1.x = vcur*kk1.x; jr1.y = vcur*kk1.y; jr1.z = vcur*kk1.z; jr1.w = vcur*kk1.w;   \
        jr2.x = vcur*kk2.x; jr2.y = vcur*kk2.y; jr2.z = vcur*kk2.z; jr2.w = vcur*kk2.w;   \
        jr3.x = vcur*kk3.x; jr3.y = vcur*kk3.y; jr3.z = vcur*kk3.z; jr3.w = vcur*kk3.w;   \
    } else if ((MODE) == 1) {                                                             \
        const float wvr = (WI) * vcur;                                                    \
        jr0.x = fmaf(jr0.x, (WF), wvr*kk0.x); jr0.y = fmaf(jr0.y, (WF), wvr*kk0.y);       \
        jr0.z = fmaf(jr0.z, (WF), wvr*kk0.z); jr0.w = fmaf(jr0.w, (WF), wvr*kk0.w);       \
        jr1.x = fmaf(jr1.x, (WF), wvr*kk1.x); jr1.y = fmaf(jr1.y, (WF), wvr*kk1.y);       \
        jr1.z = fmaf(jr1.z, (WF), wvr*kk1.z); jr1.w = fmaf(jr1.w, (WF), wvr*kk1.w);       \
        jr2.x = fmaf(jr2.x, (WF), wvr*kk2.x); jr2.y = fmaf(jr2.y, (WF), wvr*kk2.y);       \
        jr2.z = fmaf(jr2.z, (WF), wvr*kk2.z); jr2.w = fmaf(jr2.w, (WF), wvr*kk2.w);       \
        jr3.x = fmaf(jr3.x, (WF), wvr*kk3.x); jr3.y = fmaf(jr3.y, (WF), wvr*kk3.y);       \
        jr3.z = fmaf(jr3.z, (WF), wvr*kk3.z); jr3.w = fmaf(jr3.w, (WF), wvr*kk3.w);       \
    }

// ---------------------------------------------------------------------------
// Kernel 2: sequential scan, 1024 threads (16 waves, 4/SIMD).
// ROUND-12 = R11 + deeper prefetch pipelines (latency-theory test):
//  (1) stager global->LDS pipeline now 2-deep (g0 written this iter was
//      loaded 2 iters ago; HBM ~900 cyc < 2 iterations);
//  (2) wave0 chain scalars loaded 1 iteration ahead (SGPR pipeline);
//  (3) dots use 4 independent accumulators (dep depth 16 -> 4+2).
// Everything else identical to R11 (one barrier, parity wred/dec, swizzled
// ring, wave0-exclusive fp64 chain).
// ---------------------------------------------------------------------------
__global__ __launch_bounds__(1024, 4) void scan_kernel(
    const float* __restrict__ q, const float* __restrict__ k, const float* __restrict__ v,
    const float* __restrict__ U, const float* __restrict__ sl_arr,
    const float* __restrict__ kqq_arr, const float* __restrict__ vv_arr,
    const float* __restrict__ kq_adj, const float* __restrict__ vv_adj,
    const float* __restrict__ kU_adj, const double* __restrict__ invl_arr,
    float* __restrict__ out)  // [0,2048) costs | [2048,4096) updated | [4096,...) J
{
    const int tid  = threadIdx.x;
    const int lane = tid & 63;
    const int w    = __builtin_amdgcn_readfirstlane(tid >> 6);  // 0..15
    const int r    = tid >> 3;        // my row 0..127
    const int cg   = tid & 7;
    const int c0s  = cg * 20;         // swizzled LDS chunk offset

    float4 jr0 = make_float4(0.f, 0.f, 0.f, 0.f);
    float4 jr1 = jr0, jr2 = jr0, jr3 = jr0;

    __shared__ float ring[3][3][160];                 // [phase][q,u,k][swizzled]
    __shared__ __align__(16) float wred[2][16][4];    // [parity][wave][r1,r2,r3,r4]
    __shared__ __align__(16) float decLDS[2][4];      // [parity][wf,wi,mode,-]

    // stagers: waves 6..11 (tid 384..767) — wave0 stays staging-free
    const bool stager = (tid >= 384) && (tid < 768);
    const int  which  = (tid >> 7) - 3;    // 0:q 1:u 2:k (when stager)
    const int  sidx   = tid & 127;
    const int  widx   = ((sidx >> 4) * 20) + (sidx & 15);  // swizzled write idx

    // ---- prologue: stage phases 0,1; g0/g1 = 2-deep load pipeline ----
    // invariant: phase j holds q_{j+1}, u_{j+1}, k_j
    // iter i writes phase (i+2)%3 with q_{i+3}, u_{i+3}, k_{i+2}
    float g0 = 0.f, g1 = 0.f;
    if (stager) {
        if (which == 0) {
            ring[0][0][widx] = q[(size_t)1 * D + sidx];
            ring[1][0][widx] = q[(size_t)2 * D + sidx];
            g0 = q[(size_t)3 * D + sidx];   // written at iter 0
            g1 = q[(size_t)4 * D + sidx];   // written at iter 1
        } else if (which == 1) {
            ring[0][1][widx] = U[(size_t)1 * D + sidx];
            ring[1][1][widx] = U[(size_t)2 * D + sidx];
            g0 = U[(size_t)3 * D + sidx];
            g1 = U[(size_t)4 * D + sidx];
        } else {
            ring[0][2][widx] = k[sidx];
            ring[1][2][widx] = k[(size_t)1 * D + sidx];
            g0 = k[(size_t)2 * D + sidx];
            g1 = k[(size_t)3 * D + sidx];
        }
    }
    float vcur = v[r], vnext = v[(size_t)D + r], vn2 = v[(size_t)2 * D + r];

    // dec_0 is always mode 2 (first step: J_0 = v_0 k_0^T)
    float dwf = 0.f, dwi = 1.f;
    int dmode = 2;
    if (tid == 0) { decLDS[0][0] = 0.f; decLDS[0][1] = 1.f; decLDS[0][2] = 2.f; decLDS[0][3] = 0.f; }

    // ---- wave0: fp64 state + 1-iteration-ahead chain-scalar pipeline ----
    double SJ = 0.0, AJJ = 0.0, trSvv = 0.0;  // live on wave 0 only
    float  csl = 0.f, ckq = 0.f, cvv = 0.f, ckqa = 0.f, cvva = 0.f,
           cvvp = 0.f, ckua = 0.f;
    double cinv = 0.0;
    if (w == 0) {
        const double sl0 = (double)sl_arr[0];
        const double kq0 = (double)kqq_arr[0];
        const double vv0 = (double)vv_arr[0];
        trSvv = vv0;
        SJ  = sl0;
        AJJ = vv0 * kq0;
        if (lane == 0) {
            out[0] = (float)((0.5 * trSvv - SJ + 0.5 * AJJ) * invl_arr[0]);
            out[SEQ] = 1.f;
        }
        // scalars for chain-step 1 (used at iter 0)
        csl  = sl_arr[1];  ckq  = kqq_arr[1]; cvv  = vv_arr[1];
        ckqa = kq_adj[1];  cvva = vv_adj[1];  cvvp = vv_arr[0];
        ckua = kU_adj[1];  cinv = invl_arr[1];
    }
    __syncthreads();

    for (int i = 0; i < SEQ - 1; ++i) {
        const int p    = i % 3;
        const int pw   = (i + 2) % 3;
        const int par  = i & 1;
        const int parn = 1 - par;

        // ---- wave0: issue NEXT chain scalars (for step i+2, used next iter)
        float nsl = 0.f, nkq = 0.f, nvv = 0.f, nkqa = 0.f, nvva = 0.f,
              nvvp = 0.f, nkua = 0.f;
        double ninv = 0.0;
        if (w == 0) {
            const int t2 = (i + 2 < SEQ) ? i + 2 : SEQ - 1;
            nsl  = sl_arr[t2];  nkq  = kqq_arr[t2]; nvv  = vv_arr[t2];
            nkqa = kq_adj[t2];  nvva = vv_adj[t2];  nvvp = vv_arr[i + 1];
            nkua = kU_adj[t2];  ninv = invl_arr[t2];
        }

        // ---- ring reads: q_{i+1}, u_{i+1} (dot operands), k_i (update) ----
        const float4* q4 = (const float4*)&ring[p][0][c0s];
        const float4* u4 = (const float4*)&ring[p][1][c0s];
        const float4* k4 = (const float4*)&ring[p][2][c0s];
        const float4 qa = q4[0], qb = q4[1], qc = q4[2], qd = q4[3];
        const float4 ua = u4[0], ub = u4[1], uc = u4[2], ud = u4[3];
        const float4 kk0 = k4[0], kk1 = k4[1], kk2 = k4[2], kk3 = k4[3];

        // ---- dot: 4 independent accumulators (dep depth 4 + 2) ----
        float p0 = jr0.x * qa.x, p1 = jr1.x * qb.x, p2 = jr2.x * qc.x, p3 = jr3.x * qd.x;
        p0 = fmaf(jr0.y, qa.y, p0); p1 = fmaf(jr1.y, qb.y, p1);
        p2 = fmaf(jr2.y, qc.y, p2); p3 = fmaf(jr3.y, qd.y, p3);
        p0 = fmaf(jr0.z, qa.z, p0); p1 = fmaf(jr1.z, qb.z, p1);
        p2 = fmaf(jr2.z, qc.z, p2); p3 = fmaf(jr3.z, qd.z, p3);
        p0 = fmaf(jr0.w, qa.w, p0); p1 = fmaf(jr1.w, qb.w, p1);
        p2 = fmaf(jr2.w, qc.w, p2); p3 = fmaf(jr3.w, qd.w, p3);
        float Yq = (p0 + p1) + (p2 + p3);
        float s0 = jr0.x * ua.x, s1 = jr1.x * ub.x, s2 = jr2.x * uc.x, s3 = jr3.x * ud.x;
        s0 = fmaf(jr0.y, ua.y, s0); s1 = fmaf(jr1.y, ub.y, s1);
        s2 = fmaf(jr2.y, uc.y, s2); s3 = fmaf(jr3.y, ud.y, s3);
        s0 = fmaf(jr0.z, ua.z, s0); s1 = fmaf(jr1.z, ub.z, s1);
        s2 = fmaf(jr2.z, uc.z, s2); s3 = fmaf(jr3.z, ud.z, s3);
        s0 = fmaf(jr0.w, ua.w, s0); s1 = fmaf(jr1.w, ub.w, s1);
        s2 = fmaf(jr2.w, uc.w, s2); s3 = fmaf(jr3.w, ud.w, s3);
        float Yw = (s0 + s1) + (s2 + s3);

        // ---- reductions (R11 order preserved) ----
        COMBINE8(Yq);              // full (Y')_r on all 8 lanes of row r
        COMBINE8(Yw);
        float z1 = vnext * Yq;     // all x8-counted -> *0.125 in fp64 chain
        float z2 = Yq * Yq;
        float z3 = vcur  * Yq;
        float z4 = vnext * Yw;
        TAIL3(z1);
        TAIL3(z2);
        TAIL3(z3);
        TAIL3(z4);
        if (lane == 63) *(float4*)&wred[par][w][0] = make_float4(z1, z2, z3, z4);

        // ---- staging write (g0 loaded 2 iters ago) + issue next load ----
        if (stager) {
            ring[pw][which][widx] = g0;
            g0 = g1;
            const int tq = (i + 5 < SEQ) ? i + 5 : SEQ - 1;
            const int tk = (i + 4 < SEQ) ? i + 4 : SEQ - 1;
            g1 = (which == 0) ? q[(size_t)tq * D + sidx]
               : (which == 1) ? U[(size_t)tq * D + sidx]
                              : k[(size_t)tk * D + sidx];
        }
        const int tv = (i + 3 < SEQ) ? i + 3 : SEQ - 1;
        const float vnew = v[(size_t)tv * D + r];

        __syncthreads();  // the ONE barrier

        if (w == 0) {
            // issue wred read first; J-update FMAs interleave with its latency
            float4 ww = *(const float4*)&wred[par][lane & 15][0];
            const float odwf = dwf, odwi = dwi;
            const int   odmode = dmode;
            UPDATE_J(odmode, odwf, odwi)

            REDUCE16(ww.x);
            REDUCE16(ww.y);
            REDUCE16(ww.z);
            REDUCE16(ww.w);

            double a, b;
            if (odmode == 2)      { a = 0.0; b = 1.0; }
            else if (odmode == 1) { a = (double)odwf; b = (double)odwi; }
            else                  { a = 1.0; b = 0.0; }
            const double kqa = (double)ckqa, vva = (double)cvva;
            const double vvp = (double)cvvp, kua = (double)ckua;
            const double r1 = (double)ww.x * 0.125, r2 = (double)ww.y * 0.125;
            const double r3 = (double)ww.z * 0.125, r4 = (double)ww.w * 0.125;
            const double Jqv  = a * r1 + b * (kqa * vva);
            const double Jq2  = a * a * r2 + 2.0 * a * b * kqa * r3 + b * b * kqa * kqa * vvp;
            const double AJl_ = a * r4 + b * kua * vva;

            trSvv += (double)cvv;
            SJ    += Jqv;
            AJJ   += Jq2;
            const double s_l  = (double)csl;
            const double A_ll = (double)cvv * (double)ckq;
            const double AJJ_s  = (AJJ == 0.0)  ? 1.0 : AJJ;
            const double A_ll_s = (A_ll == 0.0) ? 1.0 : A_ll;
            const double denom   = AJJ * A_ll - AJl_ * AJl_;
            const double denom_s = (denom == 0.0) ? 1.0 : denom;
            const double rden = 1.0 / denom_s;
            const double wf = (A_ll * SJ - AJl_ * s_l) * rden;
            const double wi = (AJJ * s_l - AJl_ * SJ) * rden;
            double wf_c, wi_c;
            if (wi <= 0.0)      { wf_c = SJ / AJJ_s;  wi_c = 0.0; }
            else if (wf <= 0.0) { wf_c = 0.0;         wi_c = s_l / A_ll_s; }
            else                { wf_c = wf;          wi_c = wi; }
            const bool do_update = (s_l * AJJ_s - AJl_ * SJ) > 0.0;

            int mode;
            if (do_update) {
                mode = 1;
                const double nSJ = wf_c * SJ + wi_c * s_l;
                AJJ = wf_c * wf_c * AJJ + 2.0 * wf_c * wi_c * AJl_ + wi_c * wi_c * A_ll;
                SJ = nSJ;
            } else {
                mode = 0;
            }

            dwf = (float)wf_c; dwi = (float)wi_c; dmode = mode;
            if (lane == 0) {
                out[i + 1] = (float)((0.5 * trSvv - SJ + 0.5 * AJJ) * cinv);
                out[SEQ + i + 1] = mode ? 1.f : 0.f;
                *(float4*)&decLDS[parn][0] = make_float4(dwf, dwi, (float)mode, 0.f);
            }
            // shift chain-scalar pipeline
            csl = nsl; ckq = nkq; cvv = nvv; ckqa = nkqa; cvva = nvva;
            cvvp = nvvp; ckua = nkua; cinv = ninv;
        } else {
            // dec_i written by wave0 in iter i-1 (post-B1(i-1)) -> separated
            // from this read by B1(i)
            const float4 df = *(const float4*)&decLDS[par][0];
            dwf = df.x; dwi = df.y; dmode = (int)df.z;
            UPDATE_J(dmode, dwf, dwi)
        }

        vcur = vnext; vnext = vn2; vn2 = vnew;
    }

    // ---- epilogue: apply final update (dec_{SEQ-1}) and store J ----
    __syncthreads();  // make wave0's decLDS[(SEQ-1)&1] write visible
    {
        const float4 df = *(const float4*)&decLDS[(SEQ - 1) & 1][0];
        const float fwf = df.x, fwi = df.y;
        const int   fmode = (int)df.z;
        const int p = (SEQ - 1) % 3;
        const float4* k4 = (const float4*)&ring[p][2][c0s];
        const float4 kk0 = k4[0], kk1 = k4[1], kk2 = k4[2], kk3 = k4[3];
        UPDATE_J(fmode, fwf, fwi)
        float* jbase = out + 2 * SEQ + (size_t)r * D + cg * 16;
        *(float4*)(jbase + 0)  = jr0;
        *(float4*)(jbase + 4)  = jr1;
        *(float4*)(jbase + 8)  = jr2;
        *(float4*)(jbase + 12) = jr3;
    }
}

extern "C" void kernel_launch(void* const* d_in, const int* in_sizes, int n_in,
                              void* d_out, int out_size, void* d_ws, size_t ws_size,
                              hipStream_t stream) {
    (void)in_sizes; (void)n_in; (void)out_size; (void)ws_size;
    const float* q = (const float*)d_in[0];
    const float* k = (const float*)d_in[1];
    const float* v = (const float*)d_in[2];
    float* out = (float*)d_out;

    float* U      = (float*)d_ws;            // SEQ*D floats (1 MB)
    float* sl     = U + (size_t)SEQ * D;     // SEQ
    float* kqq    = sl + SEQ;                // SEQ
    float* vv     = kqq + SEQ;               // SEQ
    float* kq_adj = vv + SEQ;                // SEQ
    float* vv_adj = kq_adj + SEQ;            // SEQ
    float* kU_adj = vv_adj + SEQ;            // SEQ
    double* invl  = (double*)(kU_adj + SEQ); // SEQ doubles (8B-aligned)

    precompute_kernel<<<SEQ, 256, 0, stream>>>(q, k, v, U, sl, kqq, vv,
                                               kq_adj, vv_adj, kU_adj, invl);
    scan_kernel<<<1, 1024, 0, stream>>>(q, k, v, U, sl, kqq, vv,
                                        kq_adj, vv_adj, kU_adj, invl, out);
}